// Round 6
// baseline (218.291 us; speedup 1.0000x reference)
//
#include <hip/hip_runtime.h>

#define B_    4
#define S_    2048
#define H_    8
#define M_    (B_ * S_)   // 8192

typedef __bf16    bf16_t;
typedef _Float16  f16_t;
typedef __bf16   bf16x8 __attribute__((ext_vector_type(8)));
typedef __bf16   bf16x4 __attribute__((ext_vector_type(4)));
typedef _Float16 f16x8  __attribute__((ext_vector_type(8)));
typedef float    f32x16 __attribute__((ext_vector_type(16)));

union B8 { uint4 u; bf16x8 v; bf16_t e[8]; };
union B4 { uint2 u; bf16x4 v; bf16_t e[4]; };
union H8 { uint4 u; f16x8  v; f16_t  e[8]; };
union H4 { uint2 u; f16_t  e[4]; };

#define QSCALE 0.1803368801111204f   // 0.125 * log2(e): scores exit in log2 domain

// global -> LDS direct DMA, 16B per lane. LDS dest is wave-uniform base +
// lane*16 (HW semantics); global src is per-lane.
typedef const __attribute__((address_space(1))) unsigned int ga_u32;
typedef __attribute__((address_space(3))) unsigned int       ls_u32;
__device__ __forceinline__ void g2l16(const void* g, void* l) {
    __builtin_amdgcn_global_load_lds((ga_u32*)g, (ls_u32*)l, 16, 0, 0);
}

// ---------------------------------------------------------------------------
// x fp32 -> bf16 streaming cast. grid (1024, 3), 256 thr.
// Destinations are dead scratch: d_out (16MB, rewritten by gemm_out) holds
// Xq/Xk; the AO region (rewritten by attn) holds Xv. No ws growth.
// ---------------------------------------------------------------------------
__global__ __launch_bounds__(256) void cast_x(
    const float* __restrict__ xq, const float* __restrict__ xk,
    const float* __restrict__ xv,
    bf16_t* __restrict__ dq, bf16_t* __restrict__ dk, bf16_t* __restrict__ dv)
{
    const int z = blockIdx.y;
    const float* src = z == 0 ? xq : z == 1 ? xk : xv;
    bf16_t*      dst = z == 0 ? dq : z == 1 ? dk : dv;
    const size_t base = (size_t)blockIdx.x * 4096 + threadIdx.x * 4;
    #pragma unroll
    for (int k = 0; k < 4; ++k) {
        const size_t i = base + (size_t)k * 1024;
        float4 v = *(const float4*)(src + i);
        B4 o;
        o.e[0] = (bf16_t)v.x; o.e[1] = (bf16_t)v.y;
        o.e[2] = (bf16_t)v.z; o.e[3] = (bf16_t)v.w;
        *(uint2*)(dst + i) = o.u;
    }
}

// ---------------------------------------------------------------------------
// All weight converts in ONE launch. grid (8, 8, 4), 256 thr.
// z<3:  W[z] [8,512,64] fp32 -> Wt[z] [8,64,512] bf16 (y = head, x = k-tile)
// z==3: Wo [512,512] fp32 -> Wot [512n][512k] f16    (y = n-tile, x = k-tile)
// ---------------------------------------------------------------------------
__global__ __launch_bounds__(256) void convert_weights(
    const float* __restrict__ w0, const float* __restrict__ w1,
    const float* __restrict__ w2, const float* __restrict__ wo,
    bf16_t* __restrict__ t0, bf16_t* __restrict__ t1,
    bf16_t* __restrict__ t2, f16_t* __restrict__ wot)
{
    __shared__ float T[64][65];
    const int z   = blockIdx.z;
    const int k0  = blockIdx.x * 64;
    const int tid = threadIdx.x;
    const int row = tid & 63, q4 = tid >> 6;

    if (z < 3) {
        const float* W  = z == 0 ? w0 : z == 1 ? w1 : w2;
        bf16_t*      Wt = z == 0 ? t0 : z == 1 ? t1 : t2;
        const int h = blockIdx.y;
        const float* Wh = W + (size_t)h * 512 * 64;
        #pragma unroll
        for (int i = 0; i < 4; ++i) {
            int fq = q4 * 4 + i;
            float4 v = *(const float4*)(Wh + (size_t)(k0 + row) * 64 + fq * 4);
            T[row][fq * 4 + 0] = v.x; T[row][fq * 4 + 1] = v.y;
            T[row][fq * 4 + 2] = v.z; T[row][fq * 4 + 3] = v.w;
        }
        __syncthreads();
        bf16_t* Wth = Wt + (size_t)h * 64 * 512;
        #pragma unroll
        for (int i = 0; i < 4; ++i) {
            int kq = q4 * 4 + i;
            B4 o;
            #pragma unroll
            for (int j = 0; j < 4; ++j) o.e[j] = (bf16_t)T[kq * 4 + j][row];
            *(uint2*)(Wth + (size_t)row * 512 + k0 + kq * 4) = o.u;
        }
    } else {
        const int n0 = blockIdx.y * 64;
        #pragma unroll
        for (int i = 0; i < 4; ++i) {
            int fq = q4 * 4 + i;
            float4 v = *(const float4*)(wo + (size_t)(k0 + row) * 512 + n0 + fq * 4);
            T[row][fq * 4 + 0] = v.x; T[row][fq * 4 + 1] = v.y;
            T[row][fq * 4 + 2] = v.z; T[row][fq * 4 + 3] = v.w;
        }
        __syncthreads();
        #pragma unroll
        for (int i = 0; i < 4; ++i) {
            int kq = q4 * 4 + i;
            H4 o;
            #pragma unroll
            for (int j = 0; j < 4; ++j) o.e[j] = (f16_t)T[kq * 4 + j][row];
            *(uint2*)(wot + (size_t)(n0 + row) * 512 + k0 + kq * 4) = o.u;
        }
    }
}

// ---------------------------------------------------------------------------
// QKV projection, m97 structure: pure-bf16 operands, linear LDS [128][64]
// per matrix, global_load_lds 16B staging, 2 barriers per K-step.
// 128M x 128N x BK=64, 4 waves (2x2 of 64x64). grid (64, 4, 3) = 768 blocks.
// z==0: Q -> concat bf16 scaled QSCALE; z==1: K; z==2: V -> Vt via LDS
// transpose (coalesced 256-B strips).
// C/D: col(n)=lane&31, row(m)=(r&3)+8*(r>>2)+4*half.
// ---------------------------------------------------------------------------
__global__ __launch_bounds__(256) void proj_tiled(
    const bf16_t* __restrict__ xq, const bf16_t* __restrict__ xk,
    const bf16_t* __restrict__ xv,
    const bf16_t* __restrict__ Wtq, const bf16_t* __restrict__ Wtk,
    const bf16_t* __restrict__ Wtv,
    const float* __restrict__ bq, const float* __restrict__ bk,
    const float* __restrict__ bv,
    bf16_t* __restrict__ Qb, bf16_t* __restrict__ Kb, bf16_t* __restrict__ Vt)
{
    __shared__ char sm[34816];
    bf16_t* As = (bf16_t*)sm;
    bf16_t* Bs = As + 128 * 64;

    const int z = blockIdx.z;
    const bf16_t* X    = z == 0 ? xq  : z == 1 ? xk  : xv;
    const bf16_t* Wt   = z == 0 ? Wtq : z == 1 ? Wtk : Wtv;
    const float*  bias = z == 0 ? bq  : z == 1 ? bk  : bv;

    const int tid  = threadIdx.x;
    const int wave = tid >> 6, lane = tid & 63;
    const int l31  = lane & 31, half = lane >> 5;
    const int m0   = blockIdx.x * 128;
    const int n0   = blockIdx.y * 128;
    const int mw   = (wave & 1) * 64;
    const int nw   = (wave >> 1) * 64;

    const int srow = lane >> 3;
    const int scol = (lane & 7) * 16;

    f32x16 acc[2][2];
    #pragma unroll
    for (int mt = 0; mt < 2; ++mt)
        #pragma unroll
        for (int nt = 0; nt < 2; ++nt)
            #pragma unroll
            for (int i = 0; i < 16; ++i) acc[mt][nt][i] = 0.0f;

    for (int k0 = 0; k0 < 512; k0 += 64) {
        __syncthreads();
        #pragma unroll
        for (int i = 0; i < 4; ++i) {
            const int inst = wave * 4 + i;
            const int row  = inst * 8 + srow;
            g2l16((const char*)X  + ((size_t)(m0 + row) * 512 + k0) * 2 + scol,
                  sm + inst * 1024);
            g2l16((const char*)Wt + ((size_t)(n0 + row) * 512 + k0) * 2 + scol,
                  sm + 16384 + inst * 1024);
        }
        __syncthreads();

        #pragma unroll
        for (int kc = 0; kc < 4; ++kc) {
            B8 a0, a1, b0, b1;
            a0.u = *(const uint4*)&As[(mw + l31)      * 64 + kc * 16 + half * 8];
            a1.u = *(const uint4*)&As[(mw + 32 + l31) * 64 + kc * 16 + half * 8];
            b0.u = *(const uint4*)&Bs[(nw + l31)      * 64 + kc * 16 + half * 8];
            b1.u = *(const uint4*)&Bs[(nw + 32 + l31) * 64 + kc * 16 + half * 8];
            acc[0][0] = __builtin_amdgcn_mfma_f32_32x32x16_bf16(a0.v, b0.v, acc[0][0], 0, 0, 0);
            acc[0][1] = __builtin_amdgcn_mfma_f32_32x32x16_bf16(a0.v, b1.v, acc[0][1], 0, 0, 0);
            acc[1][0] = __builtin_amdgcn_mfma_f32_32x32x16_bf16(a1.v, b0.v, acc[1][0], 0, 0, 0);
            acc[1][1] = __builtin_amdgcn_mfma_f32_32x32x16_bf16(a1.v, b1.v, acc[1][1], 0, 0, 0);
        }
    }

    if (z <= 1) {
        const float sc_ = (z == 0) ? QSCALE : 1.0f;
        bf16_t* Out = (z == 0) ? Qb : Kb;
        #pragma unroll
        for (int mt = 0; mt < 2; ++mt)
            #pragma unroll
            for (int nt = 0; nt < 2; ++nt) {
                int n = n0 + nw + nt * 32 + l31;
                float bv_ = bias[n];
                #pragma unroll
                for (int r = 0; r < 16; ++r) {
                    int m = m0 + mw + mt * 32 + (r & 3) + 8 * (r >> 2) + 4 * half;
                    Out[(size_t)m * 512 + n] = (bf16_t)((acc[mt][nt][r] + bv_) * sc_);
                }
            }
    } else {
        const int b  = m0 >> 11;
        const int sb = m0 & 2047;
        __syncthreads();
        #pragma unroll
        for (int mt = 0; mt < 2; ++mt)
            #pragma unroll
            for (int nt = 0; nt < 2; ++nt) {
                const int nl  = nw + nt * 32 + l31;
                const float bv_ = bias[n0 + nl];
                #pragma unroll
                for (int r = 0; r < 16; r += 2) {
                    const int ml = mw + mt * 32 + (r & 3) + 8 * (r >> 2) + 4 * half;
                    union { unsigned u; bf16_t e[2]; } pk;
                    pk.e[0] = (bf16_t)(acc[mt][nt][r]     + bv_);
                    pk.e[1] = (bf16_t)(acc[mt][nt][r + 1] + bv_);
                    *(unsigned*)(sm + nl * 272 + ml * 2) = pk.u;
                }
            }
        __syncthreads();
        const int dl16 = tid >> 4;
        const int cc   = tid & 15;
        #pragma unroll
        for (int p = 0; p < 8; ++p) {
            const int d_l = p * 16 + dl16;
            const int ng  = n0 + d_l;
            const int h   = ng >> 6, dd = ng & 63;
            uint4 val = *(const uint4*)(sm + d_l * 272 + cc * 16);
            *(uint4*)(Vt + ((size_t)((b * 8 + h) * 64 + dd)) * 2048 + sb + cc * 8) = val;
        }
    }
}

// ---------------------------------------------------------------------------
// MFMA flash attention, R17: R5's 64q/wave kept (each ds_read feeds 2 MFMAs)
// but repackaged as 256-thr blocks (4 waves = 2 qsub x 2 ksplit), Q-tile 128,
// grid (16,32) = 512 blocks = 2 INDEPENDENT blocks/CU. R5 post-mortem: pipes
// balanced (MFMA 2066 / LDS 1536 / VALU 2178 cyc per iter-CU) but time =
// pipe-SUM (6600) -- 1 block/CU of barrier-locked waves cannot overlap
// staging with compute. Two unsynced blocks anti-phase: one computes while
// the other stages/drains. Waves/CU unchanged (8). Per-thread staging
// doubles (4 uint4 K + 8 uint2 V), same verified kqmap layout (each thread
// does two of the R5 jobs: rows +16r / +32r2).
// Unnormalized partials combine linearly (no-max softmax, log2 domain);
// separate lA/lB row sums for the two query halves. Q pre-scaled in proj.
// ---------------------------------------------------------------------------
__global__ __launch_bounds__(256, 2) void attn_mfma(
    const bf16_t* __restrict__ Q, const bf16_t* __restrict__ K,
    const bf16_t* __restrict__ Vt, f16_t* __restrict__ O)
{
    // staging [2][64*72] K + [2][64*72] V = 36864B; epilogue overlays
    // co[2][64][68] f32 (34816B) + cl[2][2][64] f32 (1024B)
    __shared__ char smraw[36864];
    bf16_t* KsBuf = (bf16_t*)smraw;            // [2][64*72]
    bf16_t* VsBuf = KsBuf + 2 * 64 * 72;       // [2][64*72]

    const int bh  = blockIdx.y;
    const int b   = bh >> 3, h = bh & 7;
    const int q0  = blockIdx.x * 128;
    const int tid = threadIdx.x;
    const int wave = tid >> 6, lane = tid & 63;
    const int l31 = lane & 31, half = lane >> 5;
    const int qsub = wave & 1, ksplit = wave >> 1;

    // Q fragments (B-operand: n=query=l31, k=d). 64 queries per wave:
    // half A = qsub*64 + l31, half B = +32.
    bf16x8 qfA[4], qfB[4];
    {
        const bf16_t* qp = Q + ((size_t)(b * S_ + q0 + qsub * 64 + l31)) * 512 + h * 64 + half * 8;
        #pragma unroll
        for (int ks = 0; ks < 4; ++ks) {
            B8 t;
            t.u = *(const uint4*)(qp + ks * 16);              qfA[ks] = t.v;
            t.u = *(const uint4*)(qp + 32 * 512 + ks * 16);   qfB[ks] = t.v;
        }
    }

    f32x16 oA0, oA1, oB0, oB1;
    #pragma unroll
    for (int i = 0; i < 16; ++i) { oA0[i] = 0.0f; oA1[i] = 0.0f; oB0[i] = 0.0f; oB1[i] = 0.0f; }
    float lA = 0.0f, lB = 0.0f;

    const bf16_t* Kbase = K + ((size_t)b * S_) * 512 + h * 64;
    const bf16_t* Vbase = Vt + ((size_t)bh * 64) * 2048;

    // staging: threads 0-127 fill buffer 0 (keys 0-1023), 128-255 buffer 1.
    // Each thread does two of the R5 256-thread jobs.
    const int sbuf = tid >> 7;
    const int p    = tid & 127;
    const int kr = p >> 3, kc8 = p & 7;        // kr 0..15, rows +{0,16,32,48}
    const int vd = p >> 2, vj = p & 3;         // vd 0..31, rows +{0,32}
    const int kqmap[4] = {0, 2, 1, 3};
    const int vkq = kqmap[vj];
    bf16_t* KsS = KsBuf + sbuf * (64 * 72);
    bf16_t* VsS = VsBuf + sbuf * (64 * 72);
    const bf16_t* KsC = KsBuf + ksplit * (64 * 72);
    const bf16_t* VsC = VsBuf + ksplit * (64 * 72);

    // register staging (1-deep prefetch): 4 uint4 K + 8 uint2 V per thread
    uint4 kreg[4];
    uint2 vreg[8];

#define LOADSET(TB) do {                                                      \
        _Pragma("unroll")                                                     \
        for (int r = 0; r < 4; ++r)                                           \
            kreg[r] = *(const uint4*)(Kbase + (size_t)((TB) + kr + 16 * r) * 512 + kc8 * 8); \
        _Pragma("unroll")                                                     \
        for (int r2 = 0; r2 < 2; ++r2)                                        \
            _Pragma("unroll")                                                 \
            for (int g = 0; g < 4; ++g)                                       \
                vreg[r2 * 4 + g] = *(const uint2*)(Vbase + (size_t)(vd + 32 * r2) * 2048 + (TB) + g * 16 + vkq * 4); \
    } while (0)

#define WRITESET() do {                                                       \
        _Pragma("unroll")                                                     \
        for (int r = 0; r < 4; ++r)                                           \
            *(uint4*)&KsS[(kr + 16 * r) * 72 + kc8 * 8] = kreg[r];            \
        _Pragma("unroll")                                                     \
        for (int r2 = 0; r2 < 2; ++r2)                                        \
            _Pragma("unroll")                                                 \
            for (int g = 0; g < 4; ++g)                                       \
                *(uint2*)&VsS[(vd + 32 * r2) * 72 + g * 16 + vj * 4] = vreg[r2 * 4 + g]; \
    } while (0)

    LOADSET(sbuf * 1024);

    for (int t0 = 0; t0 < 1024; t0 += 64) {
        __syncthreads();
        WRITESET();
        __syncthreads();

        // prefetch next tile AFTER the barrier: vmcnt drain lands at the
        // next iteration's first barrier, i.e. after the compute below.
        if (t0 + 64 < 1024) LOADSET(sbuf * 1024 + t0 + 64);

        // ---- S^T = K Q^T : each K fragment pair feeds BOTH query halves
        f32x16 s00, s01, s10, s11;
        #pragma unroll
        for (int i = 0; i < 16; ++i) { s00[i] = 0.0f; s01[i] = 0.0f; s10[i] = 0.0f; s11[i] = 0.0f; }
        #pragma unroll
        for (int ks = 0; ks < 4; ++ks) {
            B8 kk0, kk1;
            kk0.u = *(const uint4*)(&KsC[l31 * 72 + ks * 16 + half * 8]);
            kk1.u = *(const uint4*)(&KsC[(32 + l31) * 72 + ks * 16 + half * 8]);
            s00 = __builtin_amdgcn_mfma_f32_32x32x16_bf16(kk0.v, qfA[ks], s00, 0, 0, 0);
            s01 = __builtin_amdgcn_mfma_f32_32x32x16_bf16(kk0.v, qfB[ks], s01, 0, 0, 0);
            s10 = __builtin_amdgcn_mfma_f32_32x32x16_bf16(kk1.v, qfA[ks], s10, 0, 0, 0);
            s11 = __builtin_amdgcn_mfma_f32_32x32x16_bf16(kk1.v, qfB[ks], s11, 0, 0, 0);
        }

        // ---- p = 2^s, accumulate per-query-half sums, pack P^T frags ----
        float lsA = 0.0f, lsB = 0.0f;
        #pragma unroll
        for (int r = 0; r < 16; ++r) {
            s00[r] = __builtin_amdgcn_exp2f(s00[r]); lsA += s00[r];
            s10[r] = __builtin_amdgcn_exp2f(s10[r]); lsA += s10[r];
            s01[r] = __builtin_amdgcn_exp2f(s01[r]); lsB += s01[r];
            s11[r] = __builtin_amdgcn_exp2f(s11[r]); lsB += s11[r];
        }
        lA += lsA; lB += lsB;

        B8 pfA[4], pfB[4];
        #pragma unroll
        for (int j = 0; j < 8; ++j) {
            pfA[0].e[j] = (bf16_t)s00[j];
            pfA[1].e[j] = (bf16_t)s00[8 + j];
            pfA[2].e[j] = (bf16_t)s10[j];
            pfA[3].e[j] = (bf16_t)s10[8 + j];
            pfB[0].e[j] = (bf16_t)s01[j];
            pfB[1].e[j] = (bf16_t)s01[8 + j];
            pfB[2].e[j] = (bf16_t)s11[j];
            pfB[3].e[j] = (bf16_t)s11[8 + j];
        }

        // ---- O^T += V^T P^T : each V fragment pair feeds BOTH halves ----
        #pragma unroll
        for (int c = 0; c < 4; ++c) {
            B8 va, vb;
            va.u = *(const uint4*)(&VsC[l31 * 72 + c * 16 + half * 8]);
            vb.u = *(const uint4*)(&VsC[(32 + l31) * 72 + c * 16 + half * 8]);
            oA0 = __builtin_amdgcn_mfma_f32_32x32x16_bf16(va.v, pfA[c].v, oA0, 0, 0, 0);
            oA1 = __builtin_amdgcn_mfma_f32_32x32x16_bf16(vb.v, pfA[c].v, oA1, 0, 0, 0);
            oB0 = __builtin_amdgcn_mfma_f32_32x32x16_bf16(va.v, pfB[c].v, oB0, 0, 0, 0);
            oB1 = __builtin_amdgcn_mfma_f32_32x32x16_bf16(vb.v, pfB[c].v, oB1, 0, 0, 0);
        }
    }
#undef LOADSET
#undef WRITESET

    // ---- combine key-split partials via LDS, then normalize + store ----
    lA += __shfl_xor(lA, 32);
    lB += __shfl_xor(lB, 32);
    __syncthreads();
    float* co = (float*)smraw;                 // [2 qsub][64 reg][68]
    float* cl = co + 2 * 64 * 68;              // [2 qsub][2][64]
    if (ksplit == 1) {
        float* reg = co + qsub * (64 * 68);
        #pragma unroll
        for (int r = 0; r < 16; ++r) {
            reg[r * 68 + lane]        = oA0[r];
            reg[(16 + r) * 68 + lane] = oA1[r];
            reg[(32 + r) * 68 + lane] = oB0[r];
            reg[(48 + r) * 68 + lane] = oB1[r];
        }
        cl[qsub * 128 + lane]      = lA;
        cl[qsub * 128 + 64 + lane] = lB;
    }
    __syncthreads();
    if (ksplit == 0) {
        float* reg = co + qsub * (64 * 68);
        float invA = 1.0f / (lA + cl[qsub * 128 + lane]);
        float invB = 1.0f / (lB + cl[qsub * 128 + 64 + lane]);
        f16_t* ObA = O + ((size_t)(b * S_ + q0 + qsub * 64 + l31)) * 512 + h * 64;
        f16_t* ObB = ObA + (size_t)32 * 512;
        #pragma unroll
        for (int g = 0; g < 4; ++g) {
            H4 a, c, e, f;
            #pragma unroll
            for (int j = 0; j < 4; ++j) {
                int r = g * 4 + j;
                a.e[j] = (f16_t)((oA0[r] + reg[r * 68 + lane])        * invA);
                c.e[j] = (f16_t)((oA1[r] + reg[(16 + r) * 68 + lane]) * invA);
                e.e[j] = (f16_t)((oB0[r] + reg[(32 + r) * 68 + lane]) * invB);
                f.e[j] = (f16_t)((oB1[r] + reg[(48 + r) * 68 + lane]) * invB);
            }
            int d = 8 * g + 4 * half;
            *(uint2*)(ObA + d)      = a.u;
            *(uint2*)(ObA + 32 + d) = c.u;
            *(uint2*)(ObB + d)      = e.u;
            *(uint2*)(ObB + 32 + d) = f.u;
        }
    }
}

// ---------------------------------------------------------------------------
// LDS-tiled output GEMM, post-barrier reg prefetch: 64x64x64, 4 waves
// (2x2 of 32x32). out = AO(f16) @ Wot^T + bo, fp32. grid (128, 8), 256 thr.
// ---------------------------------------------------------------------------
__global__ __launch_bounds__(256) void gemm_out_tiled(
    const f16_t* __restrict__ A, const f16_t* __restrict__ Wot,
    const float* __restrict__ bias, float* __restrict__ C)
{
    __shared__ f16_t As[64 * 72];
    __shared__ f16_t Bs[64 * 72];

    const int tid  = threadIdx.x;
    const int wave = tid >> 6, lane = tid & 63;
    const int l31  = lane & 31, half = lane >> 5;
    const int m0   = blockIdx.x * 64;
    const int n0   = blockIdx.y * 64;
    const int mw   = (wave & 1) * 32;
    const int nw   = (wave >> 1) * 32;

    const int sr  = tid >> 2;
    const int so  = (tid & 3) * 16;

    uint4 pA0, pA1, pB0, pB1;
    {
        const f16_t* ap = A   + (size_t)(m0 + sr) * 512 + so;
        const f16_t* bp = Wot + (size_t)(n0 + sr) * 512 + so;
        pA0 = *(const uint4*)(ap); pA1 = *(const uint4*)(ap + 8);
        pB0 = *(const uint4*)(bp); pB1 = *(const uint4*)(bp + 8);
    }

    f32x16 acc;
    #pragma unroll
    for (int i = 0; i < 16; ++i) acc[i] = 0.0f;

    for (int k0 = 0; k0 < 512; k0 += 64) {
        __syncthreads();
        *(uint4*)&As[sr * 72 + so]     = pA0;
        *(uint4*)&As[sr * 72 + so + 8] = pA1;
        *(uint4*)&Bs[sr * 72 + so]     = pB0;
        *(uint4*)&Bs[sr * 72 + so + 8] = pB1;
        __syncthreads();
        if (k0 + 64 < 512) {
            const f16_t* ap = A   + (size_t)(m0 + sr) * 512 + k0 + 64 + so;
            const f16_t* bp = Wot + (size_t)(n0 + sr) * 512 + k0 + 64 + so;
            pA0 = *(const uint4*)(ap); pA1 = *(const uint4*)(ap + 8);
            pB0 = *(const uint4*)(bp); pB1 = *(const uint4*)(bp + 8);
        }

        #pragma unroll
        for (int kc = 0; kc < 4; ++kc) {
            H8 a, b;
            a.u = *(const uint4*)&As[(mw + l31) * 72 + kc * 16 + half * 8];
            b.u = *(const uint4*)&Bs[(nw + l31) * 72 + kc * 16 + half * 8];
            acc = __builtin_amdgcn_mfma_f32_32x32x16_f16(a.v, b.v, acc, 0, 0, 0);
        }
    }

    const int n = n0 + nw + l31;
    const float bias0 = bias[n];
    #pragma unroll
    for (int r = 0; r < 16; ++r) {
        int m = m0 + mw + (r & 3) + 8 * (r >> 2) + 4 * half;
        C[(size_t)m * 512 + n] = acc[r] + bias0;
    }
}

// ---------------------------------------------------------------------------
extern "C" void kernel_launch(void* const* d_in, const int* in_sizes, int n_in,
                              void* d_out, int out_size, void* d_ws, size_t ws_size,
                              hipStream_t stream)
{
    const float* x_q = (const float*)d_in[0];
    const float* x_k = (const float*)d_in[1];
    const float* x_v = (const float*)d_in[2];
    const float* Wq  = (const float*)d_in[3];
    const float* bq  = (const float*)d_in[4];
    const float* Wk  = (const float*)d_in[5];
    const float* bk  = (const float*)d_in[6];
    const float* Wv  = (const float*)d_in[7];
    const float* bv  = (const float*)d_in[8];
    const float* Wo  = (const float*)d_in[9];
    const float* bo  = (const float*)d_in[10];
    float* out = (float*)d_out;

    // ws layout (~34 MB, unchanged)
    char* W = (char*)d_ws;
    bf16_t* Wtq = (bf16_t*)W;                                    // 512 KB
    bf16_t* Wtk = Wtq + (size_t)8 * 64 * 512;
    bf16_t* Wtv = Wtk + (size_t)8 * 64 * 512;
    f16_t*  Wot = (f16_t*)(Wtv + (size_t)8 * 64 * 512);          // 512 KB
    bf16_t* Qb  = (bf16_t*)(Wot + (size_t)512 * 512);            // 8 MB
    bf16_t* Kb  = Qb + (size_t)M_ * 512;                         // 8 MB
    bf16_t* Vt  = Kb + (size_t)M_ * 512;                         // 8 MB
    f16_t*  AO  = (f16_t*)(Vt + (size_t)M_ * 512);               // 8 MB

    // bf16 X scratch lives in DEAD buffers: d_out (16MB, rewritten by
    // gemm_out_tiled) holds Xq+Xk; the AO region (rewritten by attn) holds Xv.
    bf16_t* Xqb = (bf16_t*)out;                  // 8 MB
    bf16_t* Xkb = Xqb + (size_t)M_ * 512;        // 8 MB
    bf16_t* Xvb = (bf16_t*)AO;                   // 8 MB

    cast_x<<<dim3(1024, 3), 256, 0, stream>>>(x_q, x_k, x_v, Xqb, Xkb, Xvb);

    convert_weights<<<dim3(8, 8, 4), 256, 0, stream>>>(
        Wq, Wk, Wv, Wo, Wtq, Wtk, Wtv, Wot);

    proj_tiled<<<dim3(64, 4, 3), 256, 0, stream>>>(
        Xqb, Xkb, Xvb, Wtq, Wtk, Wtv, bq, bk, bv, Qb, Kb, Vt);

    attn_mfma<<<dim3(S_ / 128, B_ * H_), 256, 0, stream>>>(Qb, Kb, Vt, AO);

    gemm_out_tiled<<<dim3(128, 8), 256, 0, stream>>>(AO, Wot, bo, out);
}

// Round 7
// 200.568 us; speedup vs baseline: 1.0884x; 1.0884x over previous
//
#include <hip/hip_runtime.h>

#define B_    4
#define S_    2048
#define H_    8
#define M_    (B_ * S_)   // 8192

typedef __bf16    bf16_t;
typedef _Float16  f16_t;
typedef __bf16   bf16x8 __attribute__((ext_vector_type(8)));
typedef __bf16   bf16x4 __attribute__((ext_vector_type(4)));
typedef _Float16 f16x8  __attribute__((ext_vector_type(8)));
typedef float    f32x16 __attribute__((ext_vector_type(16)));

union B8 { uint4 u; bf16x8 v; bf16_t e[8]; };
union B4 { uint2 u; bf16x4 v; bf16_t e[4]; };
union H8 { uint4 u; f16x8  v; f16_t  e[8]; };
union H4 { uint2 u; f16_t  e[4]; };

#define QSCALE 0.1803368801111204f   // 0.125 * log2(e): scores exit in log2 domain

// global -> LDS direct DMA, 16B per lane. LDS dest is wave-uniform base +
// lane*16 (HW semantics); global src is per-lane.
typedef const __attribute__((address_space(1))) unsigned int ga_u32;
typedef __attribute__((address_space(3))) unsigned int       ls_u32;
__device__ __forceinline__ void g2l16(const void* g, void* l) {
    __builtin_amdgcn_global_load_lds((ga_u32*)g, (ls_u32*)l, 16, 0, 0);
}

// ---------------------------------------------------------------------------
// x fp32 -> bf16 streaming cast. grid (1024, 3), 256 thr.
// Destinations are dead scratch: d_out (16MB, rewritten by gemm_out) holds
// Xq/Xk; the AO region (rewritten by attn) holds Xv. No ws growth.
// ---------------------------------------------------------------------------
__global__ __launch_bounds__(256) void cast_x(
    const float* __restrict__ xq, const float* __restrict__ xk,
    const float* __restrict__ xv,
    bf16_t* __restrict__ dq, bf16_t* __restrict__ dk, bf16_t* __restrict__ dv)
{
    const int z = blockIdx.y;
    const float* src = z == 0 ? xq : z == 1 ? xk : xv;
    bf16_t*      dst = z == 0 ? dq : z == 1 ? dk : dv;
    const size_t base = (size_t)blockIdx.x * 4096 + threadIdx.x * 4;
    #pragma unroll
    for (int k = 0; k < 4; ++k) {
        const size_t i = base + (size_t)k * 1024;
        float4 v = *(const float4*)(src + i);
        B4 o;
        o.e[0] = (bf16_t)v.x; o.e[1] = (bf16_t)v.y;
        o.e[2] = (bf16_t)v.z; o.e[3] = (bf16_t)v.w;
        *(uint2*)(dst + i) = o.u;
    }
}

// ---------------------------------------------------------------------------
// All weight converts in ONE launch. grid (8, 8, 4), 256 thr.
// z<3:  W[z] [8,512,64] fp32 -> Wt[z] [8,64,512] bf16 (y = head, x = k-tile)
// z==3: Wo [512,512] fp32 -> Wot [512n][512k] f16    (y = n-tile, x = k-tile)
// ---------------------------------------------------------------------------
__global__ __launch_bounds__(256) void convert_weights(
    const float* __restrict__ w0, const float* __restrict__ w1,
    const float* __restrict__ w2, const float* __restrict__ wo,
    bf16_t* __restrict__ t0, bf16_t* __restrict__ t1,
    bf16_t* __restrict__ t2, f16_t* __restrict__ wot)
{
    __shared__ float T[64][65];
    const int z   = blockIdx.z;
    const int k0  = blockIdx.x * 64;
    const int tid = threadIdx.x;
    const int row = tid & 63, q4 = tid >> 6;

    if (z < 3) {
        const float* W  = z == 0 ? w0 : z == 1 ? w1 : w2;
        bf16_t*      Wt = z == 0 ? t0 : z == 1 ? t1 : t2;
        const int h = blockIdx.y;
        const float* Wh = W + (size_t)h * 512 * 64;
        #pragma unroll
        for (int i = 0; i < 4; ++i) {
            int fq = q4 * 4 + i;
            float4 v = *(const float4*)(Wh + (size_t)(k0 + row) * 64 + fq * 4);
            T[row][fq * 4 + 0] = v.x; T[row][fq * 4 + 1] = v.y;
            T[row][fq * 4 + 2] = v.z; T[row][fq * 4 + 3] = v.w;
        }
        __syncthreads();
        bf16_t* Wth = Wt + (size_t)h * 64 * 512;
        #pragma unroll
        for (int i = 0; i < 4; ++i) {
            int kq = q4 * 4 + i;
            B4 o;
            #pragma unroll
            for (int j = 0; j < 4; ++j) o.e[j] = (bf16_t)T[kq * 4 + j][row];
            *(uint2*)(Wth + (size_t)row * 512 + k0 + kq * 4) = o.u;
        }
    } else {
        const int n0 = blockIdx.y * 64;
        #pragma unroll
        for (int i = 0; i < 4; ++i) {
            int fq = q4 * 4 + i;
            float4 v = *(const float4*)(wo + (size_t)(k0 + row) * 512 + n0 + fq * 4);
            T[row][fq * 4 + 0] = v.x; T[row][fq * 4 + 1] = v.y;
            T[row][fq * 4 + 2] = v.z; T[row][fq * 4 + 3] = v.w;
        }
        __syncthreads();
        #pragma unroll
        for (int i = 0; i < 4; ++i) {
            int kq = q4 * 4 + i;
            H4 o;
            #pragma unroll
            for (int j = 0; j < 4; ++j) o.e[j] = (f16_t)T[kq * 4 + j][row];
            *(uint2*)(wot + (size_t)(n0 + row) * 512 + k0 + kq * 4) = o.u;
        }
    }
}

// ---------------------------------------------------------------------------
// QKV projection, m97 structure: pure-bf16 operands, linear LDS [128][64]
// per matrix, global_load_lds 16B staging, 2 barriers per K-step.
// 128M x 128N x BK=64, 4 waves (2x2 of 64x64). grid (64, 4, 3) = 768 blocks.
// z==0: Q -> concat bf16 scaled QSCALE; z==1: K; z==2: V -> Vt via LDS
// transpose (coalesced 256-B strips).
// C/D: col(n)=lane&31, row(m)=(r&3)+8*(r>>2)+4*half.
// ---------------------------------------------------------------------------
__global__ __launch_bounds__(256) void proj_tiled(
    const bf16_t* __restrict__ xq, const bf16_t* __restrict__ xk,
    const bf16_t* __restrict__ xv,
    const bf16_t* __restrict__ Wtq, const bf16_t* __restrict__ Wtk,
    const bf16_t* __restrict__ Wtv,
    const float* __restrict__ bq, const float* __restrict__ bk,
    const float* __restrict__ bv,
    bf16_t* __restrict__ Qb, bf16_t* __restrict__ Kb, bf16_t* __restrict__ Vt)
{
    __shared__ char sm[34816];
    bf16_t* As = (bf16_t*)sm;
    bf16_t* Bs = As + 128 * 64;

    const int z = blockIdx.z;
    const bf16_t* X    = z == 0 ? xq  : z == 1 ? xk  : xv;
    const bf16_t* Wt   = z == 0 ? Wtq : z == 1 ? Wtk : Wtv;
    const float*  bias = z == 0 ? bq  : z == 1 ? bk  : bv;

    const int tid  = threadIdx.x;
    const int wave = tid >> 6, lane = tid & 63;
    const int l31  = lane & 31, half = lane >> 5;
    const int m0   = blockIdx.x * 128;
    const int n0   = blockIdx.y * 128;
    const int mw   = (wave & 1) * 64;
    const int nw   = (wave >> 1) * 64;

    const int srow = lane >> 3;
    const int scol = (lane & 7) * 16;

    f32x16 acc[2][2];
    #pragma unroll
    for (int mt = 0; mt < 2; ++mt)
        #pragma unroll
        for (int nt = 0; nt < 2; ++nt)
            #pragma unroll
            for (int i = 0; i < 16; ++i) acc[mt][nt][i] = 0.0f;

    for (int k0 = 0; k0 < 512; k0 += 64) {
        __syncthreads();
        #pragma unroll
        for (int i = 0; i < 4; ++i) {
            const int inst = wave * 4 + i;
            const int row  = inst * 8 + srow;
            g2l16((const char*)X  + ((size_t)(m0 + row) * 512 + k0) * 2 + scol,
                  sm + inst * 1024);
            g2l16((const char*)Wt + ((size_t)(n0 + row) * 512 + k0) * 2 + scol,
                  sm + 16384 + inst * 1024);
        }
        __syncthreads();

        #pragma unroll
        for (int kc = 0; kc < 4; ++kc) {
            B8 a0, a1, b0, b1;
            a0.u = *(const uint4*)&As[(mw + l31)      * 64 + kc * 16 + half * 8];
            a1.u = *(const uint4*)&As[(mw + 32 + l31) * 64 + kc * 16 + half * 8];
            b0.u = *(const uint4*)&Bs[(nw + l31)      * 64 + kc * 16 + half * 8];
            b1.u = *(const uint4*)&Bs[(nw + 32 + l31) * 64 + kc * 16 + half * 8];
            acc[0][0] = __builtin_amdgcn_mfma_f32_32x32x16_bf16(a0.v, b0.v, acc[0][0], 0, 0, 0);
            acc[0][1] = __builtin_amdgcn_mfma_f32_32x32x16_bf16(a0.v, b1.v, acc[0][1], 0, 0, 0);
            acc[1][0] = __builtin_amdgcn_mfma_f32_32x32x16_bf16(a1.v, b0.v, acc[1][0], 0, 0, 0);
            acc[1][1] = __builtin_amdgcn_mfma_f32_32x32x16_bf16(a1.v, b1.v, acc[1][1], 0, 0, 0);
        }
    }

    if (z <= 1) {
        const float sc_ = (z == 0) ? QSCALE : 1.0f;
        bf16_t* Out = (z == 0) ? Qb : Kb;
        #pragma unroll
        for (int mt = 0; mt < 2; ++mt)
            #pragma unroll
            for (int nt = 0; nt < 2; ++nt) {
                int n = n0 + nw + nt * 32 + l31;
                float bv_ = bias[n];
                #pragma unroll
                for (int r = 0; r < 16; ++r) {
                    int m = m0 + mw + mt * 32 + (r & 3) + 8 * (r >> 2) + 4 * half;
                    Out[(size_t)m * 512 + n] = (bf16_t)((acc[mt][nt][r] + bv_) * sc_);
                }
            }
    } else {
        const int b  = m0 >> 11;
        const int sb = m0 & 2047;
        __syncthreads();
        #pragma unroll
        for (int mt = 0; mt < 2; ++mt)
            #pragma unroll
            for (int nt = 0; nt < 2; ++nt) {
                const int nl  = nw + nt * 32 + l31;
                const float bv_ = bias[n0 + nl];
                #pragma unroll
                for (int r = 0; r < 16; r += 2) {
                    const int ml = mw + mt * 32 + (r & 3) + 8 * (r >> 2) + 4 * half;
                    union { unsigned u; bf16_t e[2]; } pk;
                    pk.e[0] = (bf16_t)(acc[mt][nt][r]     + bv_);
                    pk.e[1] = (bf16_t)(acc[mt][nt][r + 1] + bv_);
                    *(unsigned*)(sm + nl * 272 + ml * 2) = pk.u;
                }
            }
        __syncthreads();
        const int dl16 = tid >> 4;
        const int cc   = tid & 15;
        #pragma unroll
        for (int p = 0; p < 8; ++p) {
            const int d_l = p * 16 + dl16;
            const int ng  = n0 + d_l;
            const int h   = ng >> 6, dd = ng & 63;
            uint4 val = *(const uint4*)(sm + d_l * 272 + cc * 16);
            *(uint4*)(Vt + ((size_t)((b * 8 + h) * 64 + dd)) * 2048 + sb + cc * 8) = val;
        }
    }
}

// ---------------------------------------------------------------------------
// MFMA flash attention -- R5 version restored verbatim (best: 44.0us,
// VGPR-clean at 128, WRITE_SIZE exactly 8MB). R6's 256-thr anti-phase
// attempt spilled (+44MB scratch WRITE): its doubled staging (32 VGPR live)
// broke the 128-VGPR budget. 64 queries per wave (each ds_read feeds 2
// MFMAs); Q-tile 256/block, 8 waves = 4 qsub x 2 ksplit; grid (8,32).
// Unnormalized partials combine linearly (no-max softmax, log2 domain);
// separate lA/lB row sums for the two query halves. Q pre-scaled in proj.
// ---------------------------------------------------------------------------
__global__ __launch_bounds__(512, 2) void attn_mfma(
    const bf16_t* __restrict__ Q, const bf16_t* __restrict__ K,
    const bf16_t* __restrict__ Vt, f16_t* __restrict__ O)
{
    // staging [2][64*72] K + [2][64*72] V = 36864B; epilogue overlays
    // exchange co[4][64][68] f32 (69632B) + cl[4][2][64] f32 (2048B)
    __shared__ char smraw[71680];
    bf16_t* KsBuf = (bf16_t*)smraw;            // [2][64*72]
    bf16_t* VsBuf = KsBuf + 2 * 64 * 72;       // [2][64*72]

    const int bh  = blockIdx.y;
    const int b   = bh >> 3, h = bh & 7;
    const int q0  = blockIdx.x * 256;
    const int tid = threadIdx.x;
    const int wave = tid >> 6, lane = tid & 63;
    const int l31 = lane & 31, half = lane >> 5;
    const int qsub = wave & 3, ksplit = wave >> 2;

    // Q fragments (B-operand: n=query=l31, k=d). 64 queries per wave:
    // half A = qsub*64 + l31, half B = +32.
    bf16x8 qfA[4], qfB[4];
    {
        const bf16_t* qp = Q + ((size_t)(b * S_ + q0 + qsub * 64 + l31)) * 512 + h * 64 + half * 8;
        #pragma unroll
        for (int ks = 0; ks < 4; ++ks) {
            B8 t;
            t.u = *(const uint4*)(qp + ks * 16);              qfA[ks] = t.v;
            t.u = *(const uint4*)(qp + 32 * 512 + ks * 16);   qfB[ks] = t.v;
        }
    }

    f32x16 oA0, oA1, oB0, oB1;
    #pragma unroll
    for (int i = 0; i < 16; ++i) { oA0[i] = 0.0f; oA1[i] = 0.0f; oB0[i] = 0.0f; oB1[i] = 0.0f; }
    float lA = 0.0f, lB = 0.0f;

    const bf16_t* Kbase = K + ((size_t)b * S_) * 512 + h * 64;
    const bf16_t* Vbase = Vt + ((size_t)bh * 64) * 2048;

    // staging: threads 0-255 fill buffer 0 (keys 0-1023), 256-511 buffer 1
    const int sbuf = tid >> 8;
    const int p    = tid & 255;
    const int kr = p >> 3, kc8 = p & 7;
    const int vd = p >> 2, vj = p & 3;
    const int kqmap[4] = {0, 2, 1, 3};
    const int vkq = kqmap[vj];
    bf16_t* KsS = KsBuf + sbuf * (64 * 72);
    bf16_t* VsS = VsBuf + sbuf * (64 * 72);
    const bf16_t* KsC = KsBuf + ksplit * (64 * 72);
    const bf16_t* VsC = VsBuf + ksplit * (64 * 72);

    // register staging (1-deep prefetch): 2 uint4 K + 4 uint2 V per thread
    uint4 kreg0, kreg1;
    uint2 vreg[4];
    {
        const int tb = sbuf * 1024;
        kreg0 = *(const uint4*)(Kbase + (size_t)(tb + kr) * 512 + kc8 * 8);
        kreg1 = *(const uint4*)(Kbase + (size_t)(tb + kr + 32) * 512 + kc8 * 8);
        #pragma unroll
        for (int g = 0; g < 4; ++g)
            vreg[g] = *(const uint2*)(Vbase + (size_t)vd * 2048 + tb + g * 16 + vkq * 4);
    }

    for (int t0 = 0; t0 < 1024; t0 += 64) {
        __syncthreads();
        *(uint4*)&KsS[kr * 72 + kc8 * 8]        = kreg0;
        *(uint4*)&KsS[(kr + 32) * 72 + kc8 * 8] = kreg1;
        #pragma unroll
        for (int g = 0; g < 4; ++g)
            *(uint2*)&VsS[vd * 72 + g * 16 + vj * 4] = vreg[g];
        __syncthreads();

        // prefetch next tile AFTER the barrier: vmcnt drain lands at the
        // next iteration's first barrier, i.e. after the compute below.
        if (t0 + 64 < 1024) {
            const int tb = sbuf * 1024 + t0 + 64;
            kreg0 = *(const uint4*)(Kbase + (size_t)(tb + kr) * 512 + kc8 * 8);
            kreg1 = *(const uint4*)(Kbase + (size_t)(tb + kr + 32) * 512 + kc8 * 8);
            #pragma unroll
            for (int g = 0; g < 4; ++g)
                vreg[g] = *(const uint2*)(Vbase + (size_t)vd * 2048 + tb + g * 16 + vkq * 4);
        }

        // ---- S^T = K Q^T : each K fragment pair feeds BOTH query halves
        f32x16 s00, s01, s10, s11;
        #pragma unroll
        for (int i = 0; i < 16; ++i) { s00[i] = 0.0f; s01[i] = 0.0f; s10[i] = 0.0f; s11[i] = 0.0f; }
        #pragma unroll
        for (int ks = 0; ks < 4; ++ks) {
            B8 kk0, kk1;
            kk0.u = *(const uint4*)(&KsC[l31 * 72 + ks * 16 + half * 8]);
            kk1.u = *(const uint4*)(&KsC[(32 + l31) * 72 + ks * 16 + half * 8]);
            s00 = __builtin_amdgcn_mfma_f32_32x32x16_bf16(kk0.v, qfA[ks], s00, 0, 0, 0);
            s01 = __builtin_amdgcn_mfma_f32_32x32x16_bf16(kk0.v, qfB[ks], s01, 0, 0, 0);
            s10 = __builtin_amdgcn_mfma_f32_32x32x16_bf16(kk1.v, qfA[ks], s10, 0, 0, 0);
            s11 = __builtin_amdgcn_mfma_f32_32x32x16_bf16(kk1.v, qfB[ks], s11, 0, 0, 0);
        }

        // ---- p = 2^s, accumulate per-query-half sums, pack P^T frags ----
        float lsA = 0.0f, lsB = 0.0f;
        #pragma unroll
        for (int r = 0; r < 16; ++r) {
            s00[r] = __builtin_amdgcn_exp2f(s00[r]); lsA += s00[r];
            s10[r] = __builtin_amdgcn_exp2f(s10[r]); lsA += s10[r];
            s01[r] = __builtin_amdgcn_exp2f(s01[r]); lsB += s01[r];
            s11[r] = __builtin_amdgcn_exp2f(s11[r]); lsB += s11[r];
        }
        lA += lsA; lB += lsB;

        B8 pfA[4], pfB[4];
        #pragma unroll
        for (int j = 0; j < 8; ++j) {
            pfA[0].e[j] = (bf16_t)s00[j];
            pfA[1].e[j] = (bf16_t)s00[8 + j];
            pfA[2].e[j] = (bf16_t)s10[j];
            pfA[3].e[j] = (bf16_t)s10[8 + j];
            pfB[0].e[j] = (bf16_t)s01[j];
            pfB[1].e[j] = (bf16_t)s01[8 + j];
            pfB[2].e[j] = (bf16_t)s11[j];
            pfB[3].e[j] = (bf16_t)s11[8 + j];
        }

        // ---- O^T += V^T P^T : each V fragment pair feeds BOTH halves ----
        #pragma unroll
        for (int c = 0; c < 4; ++c) {
            B8 va, vb;
            va.u = *(const uint4*)(&VsC[l31 * 72 + c * 16 + half * 8]);
            vb.u = *(const uint4*)(&VsC[(32 + l31) * 72 + c * 16 + half * 8]);
            oA0 = __builtin_amdgcn_mfma_f32_32x32x16_bf16(va.v, pfA[c].v, oA0, 0, 0, 0);
            oA1 = __builtin_amdgcn_mfma_f32_32x32x16_bf16(vb.v, pfA[c].v, oA1, 0, 0, 0);
            oB0 = __builtin_amdgcn_mfma_f32_32x32x16_bf16(va.v, pfB[c].v, oB0, 0, 0, 0);
            oB1 = __builtin_amdgcn_mfma_f32_32x32x16_bf16(vb.v, pfB[c].v, oB1, 0, 0, 0);
        }
    }

    // ---- combine key-split partials via LDS, then normalize + store ----
    lA += __shfl_xor(lA, 32);
    lB += __shfl_xor(lB, 32);
    __syncthreads();
    float* co = (float*)smraw;                 // [4 qsub][64 reg][68]
    float* cl = co + 4 * 64 * 68;              // [4 qsub][2][64]
    if (ksplit == 1) {
        float* reg = co + qsub * (64 * 68);
        #pragma unroll
        for (int r = 0; r < 16; ++r) {
            reg[r * 68 + lane]        = oA0[r];
            reg[(16 + r) * 68 + lane] = oA1[r];
            reg[(32 + r) * 68 + lane] = oB0[r];
            reg[(48 + r) * 68 + lane] = oB1[r];
        }
        cl[qsub * 128 + lane]      = lA;
        cl[qsub * 128 + 64 + lane] = lB;
    }
    __syncthreads();
    if (ksplit == 0) {
        float* reg = co + qsub * (64 * 68);
        float invA = 1.0f / (lA + cl[qsub * 128 + lane]);
        float invB = 1.0f / (lB + cl[qsub * 128 + 64 + lane]);
        f16_t* ObA = O + ((size_t)(b * S_ + q0 + qsub * 64 + l31)) * 512 + h * 64;
        f16_t* ObB = ObA + (size_t)32 * 512;
        #pragma unroll
        for (int g = 0; g < 4; ++g) {
            H4 a, c, e, f;
            #pragma unroll
            for (int j = 0; j < 4; ++j) {
                int r = g * 4 + j;
                a.e[j] = (f16_t)((oA0[r] + reg[r * 68 + lane])        * invA);
                c.e[j] = (f16_t)((oA1[r] + reg[(16 + r) * 68 + lane]) * invA);
                e.e[j] = (f16_t)((oB0[r] + reg[(32 + r) * 68 + lane]) * invB);
                f.e[j] = (f16_t)((oB1[r] + reg[(48 + r) * 68 + lane]) * invB);
            }
            int d = 8 * g + 4 * half;
            *(uint2*)(ObA + d)      = a.u;
            *(uint2*)(ObA + 32 + d) = c.u;
            *(uint2*)(ObB + d)      = e.u;
            *(uint2*)(ObB + 32 + d) = f.u;
        }
    }
}

// ---------------------------------------------------------------------------
// Output GEMM, R18: upgraded from 64^2 tile to the proj-verified m97
// structure -- 128M x 128N x BK=64, 4 waves (2x2 of 64x64), linear LDS
// [128][64] f16, global_load_lds 16B staging, 2 barriers per K-step.
// Measured ladder: 64^2 = 343 TF vs 128^2+gload_lds = 874 TF regime.
// out = AO(f16) @ Wot^T + bo, fp32. grid (64, 4), 256 thr.
// ---------------------------------------------------------------------------
__global__ __launch_bounds__(256) void gemm_out_tiled(
    const f16_t* __restrict__ A, const f16_t* __restrict__ Wot,
    const float* __restrict__ bias, float* __restrict__ C)
{
    __shared__ char sm[32768];
    f16_t* As = (f16_t*)sm;
    f16_t* Bs = As + 128 * 64;

    const int tid  = threadIdx.x;
    const int wave = tid >> 6, lane = tid & 63;
    const int l31  = lane & 31, half = lane >> 5;
    const int m0   = blockIdx.x * 128;
    const int n0   = blockIdx.y * 128;
    const int mw   = (wave & 1) * 64;
    const int nw   = (wave >> 1) * 64;

    const int srow = lane >> 3;
    const int scol = (lane & 7) * 16;

    f32x16 acc[2][2];
    #pragma unroll
    for (int mt = 0; mt < 2; ++mt)
        #pragma unroll
        for (int nt = 0; nt < 2; ++nt)
            #pragma unroll
            for (int i = 0; i < 16; ++i) acc[mt][nt][i] = 0.0f;

    for (int k0 = 0; k0 < 512; k0 += 64) {
        __syncthreads();
        #pragma unroll
        for (int i = 0; i < 4; ++i) {
            const int inst = wave * 4 + i;
            const int row  = inst * 8 + srow;
            g2l16((const char*)A   + ((size_t)(m0 + row) * 512 + k0) * 2 + scol,
                  sm + inst * 1024);
            g2l16((const char*)Wot + ((size_t)(n0 + row) * 512 + k0) * 2 + scol,
                  sm + 16384 + inst * 1024);
        }
        __syncthreads();

        #pragma unroll
        for (int kc = 0; kc < 4; ++kc) {
            H8 a0, a1, b0, b1;
            a0.u = *(const uint4*)&As[(mw + l31)      * 64 + kc * 16 + half * 8];
            a1.u = *(const uint4*)&As[(mw + 32 + l31) * 64 + kc * 16 + half * 8];
            b0.u = *(const uint4*)&Bs[(nw + l31)      * 64 + kc * 16 + half * 8];
            b1.u = *(const uint4*)&Bs[(nw + 32 + l31) * 64 + kc * 16 + half * 8];
            acc[0][0] = __builtin_amdgcn_mfma_f32_32x32x16_f16(a0.v, b0.v, acc[0][0], 0, 0, 0);
            acc[0][1] = __builtin_amdgcn_mfma_f32_32x32x16_f16(a0.v, b1.v, acc[0][1], 0, 0, 0);
            acc[1][0] = __builtin_amdgcn_mfma_f32_32x32x16_f16(a1.v, b0.v, acc[1][0], 0, 0, 0);
            acc[1][1] = __builtin_amdgcn_mfma_f32_32x32x16_f16(a1.v, b1.v, acc[1][1], 0, 0, 0);
        }
    }

    #pragma unroll
    for (int mt = 0; mt < 2; ++mt)
        #pragma unroll
        for (int nt = 0; nt < 2; ++nt) {
            int n = n0 + nw + nt * 32 + l31;
            float bias0 = bias[n];
            #pragma unroll
            for (int r = 0; r < 16; ++r) {
                int m = m0 + mw + mt * 32 + (r & 3) + 8 * (r >> 2) + 4 * half;
                C[(size_t)m * 512 + n] = acc[mt][nt][r] + bias0;
            }
        }
}

// ---------------------------------------------------------------------------
extern "C" void kernel_launch(void* const* d_in, const int* in_sizes, int n_in,
                              void* d_out, int out_size, void* d_ws, size_t ws_size,
                              hipStream_t stream)
{
    const float* x_q = (const float*)d_in[0];
    const float* x_k = (const float*)d_in[1];
    const float* x_v = (const float*)d_in[2];
    const float* Wq  = (const float*)d_in[3];
    const float* bq  = (const float*)d_in[4];
    const float* Wk  = (const float*)d_in[5];
    const float* bk  = (const float*)d_in[6];
    const float* Wv  = (const float*)d_in[7];
    const float* bv  = (const float*)d_in[8];
    const float* Wo  = (const float*)d_in[9];
    const float* bo  = (const float*)d_in[10];
    float* out = (float*)d_out;

    // ws layout (~34 MB, unchanged)
    char* W = (char*)d_ws;
    bf16_t* Wtq = (bf16_t*)W;                                    // 512 KB
    bf16_t* Wtk = Wtq + (size_t)8 * 64 * 512;
    bf16_t* Wtv = Wtk + (size_t)8 * 64 * 512;
    f16_t*  Wot = (f16_t*)(Wtv + (size_t)8 * 64 * 512);          // 512 KB
    bf16_t* Qb  = (bf16_t*)(Wot + (size_t)512 * 512);            // 8 MB
    bf16_t* Kb  = Qb + (size_t)M_ * 512;                         // 8 MB
    bf16_t* Vt  = Kb + (size_t)M_ * 512;                         // 8 MB
    f16_t*  AO  = (f16_t*)(Vt + (size_t)M_ * 512);               // 8 MB

    // bf16 X scratch lives in DEAD buffers: d_out (16MB, rewritten by
    // gemm_out_tiled) holds Xq+Xk; the AO region (rewritten by attn) holds Xv.
    bf16_t* Xqb = (bf16_t*)out;                  // 8 MB
    bf16_t* Xkb = Xqb + (size_t)M_ * 512;        // 8 MB
    bf16_t* Xvb = (bf16_t*)AO;                   // 8 MB

    cast_x<<<dim3(1024, 3), 256, 0, stream>>>(x_q, x_k, x_v, Xqb, Xkb, Xvb);

    convert_weights<<<dim3(8, 8, 4), 256, 0, stream>>>(
        Wq, Wk, Wv, Wo, Wtq, Wtk, Wtv, Wot);

    proj_tiled<<<dim3(64, 4, 3), 256, 0, stream>>>(
        Xqb, Xkb, Xvb, Wtq, Wtk, Wtv, bq, bk, bv, Qb, Kb, Vt);

    attn_mfma<<<dim3(S_ / 256, B_ * H_), 512, 0, stream>>>(Qb, Kb, Vt, AO);

    gemm_out_tiled<<<dim3(64, 4), 256, 0, stream>>>(AO, Wot, bo, out);
}

// Round 8
// 190.573 us; speedup vs baseline: 1.1454x; 1.0524x over previous
//
#include <hip/hip_runtime.h>

#define B_    4
#define S_    2048
#define H_    8
#define M_    (B_ * S_)   // 8192

typedef __bf16    bf16_t;
typedef _Float16  f16_t;
typedef __bf16   bf16x8 __attribute__((ext_vector_type(8)));
typedef __bf16   bf16x4 __attribute__((ext_vector_type(4)));
typedef _Float16 f16x8  __attribute__((ext_vector_type(8)));
typedef float    f32x16 __attribute__((ext_vector_type(16)));

union B8 { uint4 u; bf16x8 v; bf16_t e[8]; };
union B4 { uint2 u; bf16x4 v; bf16_t e[4]; };
union H8 { uint4 u; f16x8  v; f16_t  e[8]; };
union H4 { uint2 u; f16_t  e[4]; };

#define QSCALE 0.1803368801111204f   // 0.125 * log2(e): scores exit in log2 domain

// global -> LDS direct DMA, 16B per lane. LDS dest is wave-uniform base +
// lane*16 (HW semantics); global src is per-lane.
typedef const __attribute__((address_space(1))) unsigned int ga_u32;
typedef __attribute__((address_space(3))) unsigned int       ls_u32;
__device__ __forceinline__ void g2l16(const void* g, void* l) {
    __builtin_amdgcn_global_load_lds((ga_u32*)g, (ls_u32*)l, 16, 0, 0);
}

// ---------------------------------------------------------------------------
// prep = cast_x + convert_weights MERGED into one launch (R8: dur_us residue
// ~70us over kernel-sum suggests ~10us/launch graph overhead; cast and
// convert are independent -> one fewer launch gap). grid 3328 x 256 thr.
//   blocks [0,3072):  x fp32 -> bf16 cast, 16B stores (G13: 8 bf16/lane).
//                     bid>>10 = z (xq/xk/xv), bid&1023 = 4096-elem chunk.
//   blocks [3072,3328): weight converts, cid = bid-3072:
//     z=cid>>6 <3: W[z][8,512,64] fp32 -> Wt[z][8,64,512] bf16 (head=rem>>3)
//     z==3:        Wo[512,512] fp32 -> Wot[512n][512k] f16   (n0=rem>>3)
// ---------------------------------------------------------------------------
__global__ __launch_bounds__(256) void prep(
    const float* __restrict__ xq, const float* __restrict__ xk,
    const float* __restrict__ xv,
    bf16_t* __restrict__ dq, bf16_t* __restrict__ dk, bf16_t* __restrict__ dv,
    const float* __restrict__ w0, const float* __restrict__ w1,
    const float* __restrict__ w2, const float* __restrict__ wo,
    bf16_t* __restrict__ t0, bf16_t* __restrict__ t1,
    bf16_t* __restrict__ t2, f16_t* __restrict__ wot)
{
    __shared__ float T[64][65];
    const int bid = blockIdx.x;
    const int tid = threadIdx.x;

    if (bid < 3072) {
        // ---- cast path ----
        const int z  = bid >> 10;
        const int bx = bid & 1023;
        const float* src = z == 0 ? xq : z == 1 ? xk : xv;
        bf16_t*      dst = z == 0 ? dq : z == 1 ? dk : dv;
        const size_t base = (size_t)bx * 4096 + tid * 8;
        #pragma unroll
        for (int k = 0; k < 2; ++k) {
            const size_t i = base + (size_t)k * 2048;
            float4 a = *(const float4*)(src + i);
            float4 b = *(const float4*)(src + i + 4);
            B8 o;
            o.e[0] = (bf16_t)a.x; o.e[1] = (bf16_t)a.y;
            o.e[2] = (bf16_t)a.z; o.e[3] = (bf16_t)a.w;
            o.e[4] = (bf16_t)b.x; o.e[5] = (bf16_t)b.y;
            o.e[6] = (bf16_t)b.z; o.e[7] = (bf16_t)b.w;
            *(uint4*)(dst + i) = o.u;
        }
        return;
    }

    // ---- convert path ----
    const int cid = bid - 3072;
    const int z   = cid >> 6;
    const int rem = cid & 63;
    const int k0  = (rem & 7) * 64;
    const int row = tid & 63, q4 = tid >> 6;

    if (z < 3) {
        const float* W  = z == 0 ? w0 : z == 1 ? w1 : w2;
        bf16_t*      Wt = z == 0 ? t0 : z == 1 ? t1 : t2;
        const int h = rem >> 3;
        const float* Wh = W + (size_t)h * 512 * 64;
        #pragma unroll
        for (int i = 0; i < 4; ++i) {
            int fq = q4 * 4 + i;
            float4 v = *(const float4*)(Wh + (size_t)(k0 + row) * 64 + fq * 4);
            T[row][fq * 4 + 0] = v.x; T[row][fq * 4 + 1] = v.y;
            T[row][fq * 4 + 2] = v.z; T[row][fq * 4 + 3] = v.w;
        }
        __syncthreads();
        bf16_t* Wth = Wt + (size_t)h * 64 * 512;
        #pragma unroll
        for (int i = 0; i < 4; ++i) {
            int kq = q4 * 4 + i;
            B4 o;
            #pragma unroll
            for (int j = 0; j < 4; ++j) o.e[j] = (bf16_t)T[kq * 4 + j][row];
            *(uint2*)(Wth + (size_t)row * 512 + k0 + kq * 4) = o.u;
        }
    } else {
        const int n0 = (rem >> 3) * 64;
        #pragma unroll
        for (int i = 0; i < 4; ++i) {
            int fq = q4 * 4 + i;
            float4 v = *(const float4*)(wo + (size_t)(k0 + row) * 512 + n0 + fq * 4);
            T[row][fq * 4 + 0] = v.x; T[row][fq * 4 + 1] = v.y;
            T[row][fq * 4 + 2] = v.z; T[row][fq * 4 + 3] = v.w;
        }
        __syncthreads();
        #pragma unroll
        for (int i = 0; i < 4; ++i) {
            int kq = q4 * 4 + i;
            H4 o;
            #pragma unroll
            for (int j = 0; j < 4; ++j) o.e[j] = (f16_t)T[kq * 4 + j][row];
            *(uint2*)(wot + (size_t)(n0 + row) * 512 + k0 + kq * 4) = o.u;
        }
    }
}

// ---------------------------------------------------------------------------
// QKV projection, m97 structure: pure-bf16 operands, linear LDS [128][64]
// per matrix, global_load_lds 16B staging, 2 barriers per K-step.
// 128M x 128N x BK=64, 4 waves (2x2 of 64x64). grid (64, 4, 3) = 768 blocks.
// z==0: Q -> concat bf16 scaled QSCALE; z==1: K; z==2: V -> Vt via LDS
// transpose (coalesced 256-B strips).
// C/D: col(n)=lane&31, row(m)=(r&3)+8*(r>>2)+4*half.
// ---------------------------------------------------------------------------
__global__ __launch_bounds__(256) void proj_tiled(
    const bf16_t* __restrict__ xq, const bf16_t* __restrict__ xk,
    const bf16_t* __restrict__ xv,
    const bf16_t* __restrict__ Wtq, const bf16_t* __restrict__ Wtk,
    const bf16_t* __restrict__ Wtv,
    const float* __restrict__ bq, const float* __restrict__ bk,
    const float* __restrict__ bv,
    bf16_t* __restrict__ Qb, bf16_t* __restrict__ Kb, bf16_t* __restrict__ Vt)
{
    __shared__ char sm[34816];
    bf16_t* As = (bf16_t*)sm;
    bf16_t* Bs = As + 128 * 64;

    const int z = blockIdx.z;
    const bf16_t* X    = z == 0 ? xq  : z == 1 ? xk  : xv;
    const bf16_t* Wt   = z == 0 ? Wtq : z == 1 ? Wtk : Wtv;
    const float*  bias = z == 0 ? bq  : z == 1 ? bk  : bv;

    const int tid  = threadIdx.x;
    const int wave = tid >> 6, lane = tid & 63;
    const int l31  = lane & 31, half = lane >> 5;
    const int m0   = blockIdx.x * 128;
    const int n0   = blockIdx.y * 128;
    const int mw   = (wave & 1) * 64;
    const int nw   = (wave >> 1) * 64;

    const int srow = lane >> 3;
    const int scol = (lane & 7) * 16;

    f32x16 acc[2][2];
    #pragma unroll
    for (int mt = 0; mt < 2; ++mt)
        #pragma unroll
        for (int nt = 0; nt < 2; ++nt)
            #pragma unroll
            for (int i = 0; i < 16; ++i) acc[mt][nt][i] = 0.0f;

    for (int k0 = 0; k0 < 512; k0 += 64) {
        __syncthreads();
        #pragma unroll
        for (int i = 0; i < 4; ++i) {
            const int inst = wave * 4 + i;
            const int row  = inst * 8 + srow;
            g2l16((const char*)X  + ((size_t)(m0 + row) * 512 + k0) * 2 + scol,
                  sm + inst * 1024);
            g2l16((const char*)Wt + ((size_t)(n0 + row) * 512 + k0) * 2 + scol,
                  sm + 16384 + inst * 1024);
        }
        __syncthreads();

        #pragma unroll
        for (int kc = 0; kc < 4; ++kc) {
            B8 a0, a1, b0, b1;
            a0.u = *(const uint4*)&As[(mw + l31)      * 64 + kc * 16 + half * 8];
            a1.u = *(const uint4*)&As[(mw + 32 + l31) * 64 + kc * 16 + half * 8];
            b0.u = *(const uint4*)&Bs[(nw + l31)      * 64 + kc * 16 + half * 8];
            b1.u = *(const uint4*)&Bs[(nw + 32 + l31) * 64 + kc * 16 + half * 8];
            acc[0][0] = __builtin_amdgcn_mfma_f32_32x32x16_bf16(a0.v, b0.v, acc[0][0], 0, 0, 0);
            acc[0][1] = __builtin_amdgcn_mfma_f32_32x32x16_bf16(a0.v, b1.v, acc[0][1], 0, 0, 0);
            acc[1][0] = __builtin_amdgcn_mfma_f32_32x32x16_bf16(a1.v, b0.v, acc[1][0], 0, 0, 0);
            acc[1][1] = __builtin_amdgcn_mfma_f32_32x32x16_bf16(a1.v, b1.v, acc[1][1], 0, 0, 0);
        }
    }

    if (z <= 1) {
        const float sc_ = (z == 0) ? QSCALE : 1.0f;
        bf16_t* Out = (z == 0) ? Qb : Kb;
        #pragma unroll
        for (int mt = 0; mt < 2; ++mt)
            #pragma unroll
            for (int nt = 0; nt < 2; ++nt) {
                int n = n0 + nw + nt * 32 + l31;
                float bv_ = bias[n];
                #pragma unroll
                for (int r = 0; r < 16; ++r) {
                    int m = m0 + mw + mt * 32 + (r & 3) + 8 * (r >> 2) + 4 * half;
                    Out[(size_t)m * 512 + n] = (bf16_t)((acc[mt][nt][r] + bv_) * sc_);
                }
            }
    } else {
        const int b  = m0 >> 11;
        const int sb = m0 & 2047;
        __syncthreads();
        #pragma unroll
        for (int mt = 0; mt < 2; ++mt)
            #pragma unroll
            for (int nt = 0; nt < 2; ++nt) {
                const int nl  = nw + nt * 32 + l31;
                const float bv_ = bias[n0 + nl];
                #pragma unroll
                for (int r = 0; r < 16; r += 2) {
                    const int ml = mw + mt * 32 + (r & 3) + 8 * (r >> 2) + 4 * half;
                    union { unsigned u; bf16_t e[2]; } pk;
                    pk.e[0] = (bf16_t)(acc[mt][nt][r]     + bv_);
                    pk.e[1] = (bf16_t)(acc[mt][nt][r + 1] + bv_);
                    *(unsigned*)(sm + nl * 272 + ml * 2) = pk.u;
                }
            }
        __syncthreads();
        const int dl16 = tid >> 4;
        const int cc   = tid & 15;
        #pragma unroll
        for (int p = 0; p < 8; ++p) {
            const int d_l = p * 16 + dl16;
            const int ng  = n0 + d_l;
            const int h   = ng >> 6, dd = ng & 63;
            uint4 val = *(const uint4*)(sm + d_l * 272 + cc * 16);
            *(uint4*)(Vt + ((size_t)((b * 8 + h) * 64 + dd)) * 2048 + sb + cc * 8) = val;
        }
    }
}

// ---------------------------------------------------------------------------
// MFMA flash attention -- R5 version (best: 43.4us, VGPR-clean at 128,
// WRITE_SIZE exactly 8MB). 64 queries per wave (each ds_read feeds 2 MFMAs);
// Q-tile 256/block, 8 waves = 4 qsub x 2 ksplit; grid (8,32).
// Unnormalized partials combine linearly (no-max softmax, log2 domain);
// separate lA/lB row sums for the two query halves. Q pre-scaled in proj.
// ---------------------------------------------------------------------------
__global__ __launch_bounds__(512, 2) void attn_mfma(
    const bf16_t* __restrict__ Q, const bf16_t* __restrict__ K,
    const bf16_t* __restrict__ Vt, f16_t* __restrict__ O)
{
    // staging [2][64*72] K + [2][64*72] V = 36864B; epilogue overlays
    // exchange co[4][64][68] f32 (69632B) + cl[4][2][64] f32 (2048B)
    __shared__ char smraw[71680];
    bf16_t* KsBuf = (bf16_t*)smraw;            // [2][64*72]
    bf16_t* VsBuf = KsBuf + 2 * 64 * 72;       // [2][64*72]

    const int bh  = blockIdx.y;
    const int b   = bh >> 3, h = bh & 7;
    const int q0  = blockIdx.x * 256;
    const int tid = threadIdx.x;
    const int wave = tid >> 6, lane = tid & 63;
    const int l31 = lane & 31, half = lane >> 5;
    const int qsub = wave & 3, ksplit = wave >> 2;

    // Q fragments (B-operand: n=query=l31, k=d). 64 queries per wave:
    // half A = qsub*64 + l31, half B = +32.
    bf16x8 qfA[4], qfB[4];
    {
        const bf16_t* qp = Q + ((size_t)(b * S_ + q0 + qsub * 64 + l31)) * 512 + h * 64 + half * 8;
        #pragma unroll
        for (int ks = 0; ks < 4; ++ks) {
            B8 t;
            t.u = *(const uint4*)(qp + ks * 16);              qfA[ks] = t.v;
            t.u = *(const uint4*)(qp + 32 * 512 + ks * 16);   qfB[ks] = t.v;
        }
    }

    f32x16 oA0, oA1, oB0, oB1;
    #pragma unroll
    for (int i = 0; i < 16; ++i) { oA0[i] = 0.0f; oA1[i] = 0.0f; oB0[i] = 0.0f; oB1[i] = 0.0f; }
    float lA = 0.0f, lB = 0.0f;

    const bf16_t* Kbase = K + ((size_t)b * S_) * 512 + h * 64;
    const bf16_t* Vbase = Vt + ((size_t)bh * 64) * 2048;

    // staging: threads 0-255 fill buffer 0 (keys 0-1023), 256-511 buffer 1
    const int sbuf = tid >> 8;
    const int p    = tid & 255;
    const int kr = p >> 3, kc8 = p & 7;
    const int vd = p >> 2, vj = p & 3;
    const int kqmap[4] = {0, 2, 1, 3};
    const int vkq = kqmap[vj];
    bf16_t* KsS = KsBuf + sbuf * (64 * 72);
    bf16_t* VsS = VsBuf + sbuf * (64 * 72);
    const bf16_t* KsC = KsBuf + ksplit * (64 * 72);
    const bf16_t* VsC = VsBuf + ksplit * (64 * 72);

    // register staging (1-deep prefetch): 2 uint4 K + 4 uint2 V per thread
    uint4 kreg0, kreg1;
    uint2 vreg[4];
    {
        const int tb = sbuf * 1024;
        kreg0 = *(const uint4*)(Kbase + (size_t)(tb + kr) * 512 + kc8 * 8);
        kreg1 = *(const uint4*)(Kbase + (size_t)(tb + kr + 32) * 512 + kc8 * 8);
        #pragma unroll
        for (int g = 0; g < 4; ++g)
            vreg[g] = *(const uint2*)(Vbase + (size_t)vd * 2048 + tb + g * 16 + vkq * 4);
    }

    for (int t0 = 0; t0 < 1024; t0 += 64) {
        __syncthreads();
        *(uint4*)&KsS[kr * 72 + kc8 * 8]        = kreg0;
        *(uint4*)&KsS[(kr + 32) * 72 + kc8 * 8] = kreg1;
        #pragma unroll
        for (int g = 0; g < 4; ++g)
            *(uint2*)&VsS[vd * 72 + g * 16 + vj * 4] = vreg[g];
        __syncthreads();

        // prefetch next tile AFTER the barrier: vmcnt drain lands at the
        // next iteration's first barrier, i.e. after the compute below.
        if (t0 + 64 < 1024) {
            const int tb = sbuf * 1024 + t0 + 64;
            kreg0 = *(const uint4*)(Kbase + (size_t)(tb + kr) * 512 + kc8 * 8);
            kreg1 = *(const uint4*)(Kbase + (size_t)(tb + kr + 32) * 512 + kc8 * 8);
            #pragma unroll
            for (int g = 0; g < 4; ++g)
                vreg[g] = *(const uint2*)(Vbase + (size_t)vd * 2048 + tb + g * 16 + vkq * 4);
        }

        // ---- S^T = K Q^T : each K fragment pair feeds BOTH query halves
        f32x16 s00, s01, s10, s11;
        #pragma unroll
        for (int i = 0; i < 16; ++i) { s00[i] = 0.0f; s01[i] = 0.0f; s10[i] = 0.0f; s11[i] = 0.0f; }
        #pragma unroll
        for (int ks = 0; ks < 4; ++ks) {
            B8 kk0, kk1;
            kk0.u = *(const uint4*)(&KsC[l31 * 72 + ks * 16 + half * 8]);
            kk1.u = *(const uint4*)(&KsC[(32 + l31) * 72 + ks * 16 + half * 8]);
            s00 = __builtin_amdgcn_mfma_f32_32x32x16_bf16(kk0.v, qfA[ks], s00, 0, 0, 0);
            s01 = __builtin_amdgcn_mfma_f32_32x32x16_bf16(kk0.v, qfB[ks], s01, 0, 0, 0);
            s10 = __builtin_amdgcn_mfma_f32_32x32x16_bf16(kk1.v, qfA[ks], s10, 0, 0, 0);
            s11 = __builtin_amdgcn_mfma_f32_32x32x16_bf16(kk1.v, qfB[ks], s11, 0, 0, 0);
        }

        // ---- p = 2^s, accumulate per-query-half sums, pack P^T frags ----
        float lsA = 0.0f, lsB = 0.0f;
        #pragma unroll
        for (int r = 0; r < 16; ++r) {
            s00[r] = __builtin_amdgcn_exp2f(s00[r]); lsA += s00[r];
            s10[r] = __builtin_amdgcn_exp2f(s10[r]); lsA += s10[r];
            s01[r] = __builtin_amdgcn_exp2f(s01[r]); lsB += s01[r];
            s11[r] = __builtin_amdgcn_exp2f(s11[r]); lsB += s11[r];
        }
        lA += lsA; lB += lsB;

        B8 pfA[4], pfB[4];
        #pragma unroll
        for (int j = 0; j < 8; ++j) {
            pfA[0].e[j] = (bf16_t)s00[j];
            pfA[1].e[j] = (bf16_t)s00[8 + j];
            pfA[2].e[j] = (bf16_t)s10[j];
            pfA[3].e[j] = (bf16_t)s10[8 + j];
            pfB[0].e[j] = (bf16_t)s01[j];
            pfB[1].e[j] = (bf16_t)s01[8 + j];
            pfB[2].e[j] = (bf16_t)s11[j];
            pfB[3].e[j] = (bf16_t)s11[8 + j];
        }

        // ---- O^T += V^T P^T : each V fragment pair feeds BOTH halves ----
        #pragma unroll
        for (int c = 0; c < 4; ++c) {
            B8 va, vb;
            va.u = *(const uint4*)(&VsC[l31 * 72 + c * 16 + half * 8]);
            vb.u = *(const uint4*)(&VsC[(32 + l31) * 72 + c * 16 + half * 8]);
            oA0 = __builtin_amdgcn_mfma_f32_32x32x16_bf16(va.v, pfA[c].v, oA0, 0, 0, 0);
            oA1 = __builtin_amdgcn_mfma_f32_32x32x16_bf16(vb.v, pfA[c].v, oA1, 0, 0, 0);
            oB0 = __builtin_amdgcn_mfma_f32_32x32x16_bf16(va.v, pfB[c].v, oB0, 0, 0, 0);
            oB1 = __builtin_amdgcn_mfma_f32_32x32x16_bf16(vb.v, pfB[c].v, oB1, 0, 0, 0);
        }
    }

    // ---- combine key-split partials via LDS, then normalize + store ----
    lA += __shfl_xor(lA, 32);
    lB += __shfl_xor(lB, 32);
    __syncthreads();
    float* co = (float*)smraw;                 // [4 qsub][64 reg][68]
    float* cl = co + 4 * 64 * 68;              // [4 qsub][2][64]
    if (ksplit == 1) {
        float* reg = co + qsub * (64 * 68);
        #pragma unroll
        for (int r = 0; r < 16; ++r) {
            reg[r * 68 + lane]        = oA0[r];
            reg[(16 + r) * 68 + lane] = oA1[r];
            reg[(32 + r) * 68 + lane] = oB0[r];
            reg[(48 + r) * 68 + lane] = oB1[r];
        }
        cl[qsub * 128 + lane]      = lA;
        cl[qsub * 128 + 64 + lane] = lB;
    }
    __syncthreads();
    if (ksplit == 0) {
        float* reg = co + qsub * (64 * 68);
        float invA = 1.0f / (lA + cl[qsub * 128 + lane]);
        float invB = 1.0f / (lB + cl[qsub * 128 + 64 + lane]);
        f16_t* ObA = O + ((size_t)(b * S_ + q0 + qsub * 64 + l31)) * 512 + h * 64;
        f16_t* ObB = ObA + (size_t)32 * 512;
        #pragma unroll
        for (int g = 0; g < 4; ++g) {
            H4 a, c, e, f;
            #pragma unroll
            for (int j = 0; j < 4; ++j) {
                int r = g * 4 + j;
                a.e[j] = (f16_t)((oA0[r] + reg[r * 68 + lane])        * invA);
                c.e[j] = (f16_t)((oA1[r] + reg[(16 + r) * 68 + lane]) * invA);
                e.e[j] = (f16_t)((oB0[r] + reg[(32 + r) * 68 + lane]) * invB);
                f.e[j] = (f16_t)((oB1[r] + reg[(48 + r) * 68 + lane]) * invB);
            }
            int d = 8 * g + 4 * half;
            *(uint2*)(ObA + d)      = a.u;
            *(uint2*)(ObA + 32 + d) = c.u;
            *(uint2*)(ObB + d)      = e.u;
            *(uint2*)(ObB + 32 + d) = f.u;
        }
    }
}

// ---------------------------------------------------------------------------
// LDS-tiled output GEMM -- R5 64^2 version RESTORED (R7's 128^2 at grid
// (64,4)=1 block/CU, 4 waves, was latency-starved: non-attn total +6us).
// 64x64x64, 4 waves (2x2 of 32x32), post-barrier reg prefetch.
// out = AO(f16) @ Wot^T + bo, fp32. grid (128, 8) = 1024 blocks, 256 thr.
// ---------------------------------------------------------------------------
__global__ __launch_bounds__(256) void gemm_out_tiled(
    const f16_t* __restrict__ A, const f16_t* __restrict__ Wot,
    const float* __restrict__ bias, float* __restrict__ C)
{
    __shared__ f16_t As[64 * 72];
    __shared__ f16_t Bs[64 * 72];

    const int tid  = threadIdx.x;
    const int wave = tid >> 6, lane = tid & 63;
    const int l31  = lane & 31, half = lane >> 5;
    const int m0   = blockIdx.x * 64;
    const int n0   = blockIdx.y * 64;
    const int mw   = (wave & 1) * 32;
    const int nw   = (wave >> 1) * 32;

    const int sr  = tid >> 2;
    const int so  = (tid & 3) * 16;

    uint4 pA0, pA1, pB0, pB1;
    {
        const f16_t* ap = A   + (size_t)(m0 + sr) * 512 + so;
        const f16_t* bp = Wot + (size_t)(n0 + sr) * 512 + so;
        pA0 = *(const uint4*)(ap); pA1 = *(const uint4*)(ap + 8);
        pB0 = *(const uint4*)(bp); pB1 = *(const uint4*)(bp + 8);
    }

    f32x16 acc;
    #pragma unroll
    for (int i = 0; i < 16; ++i) acc[i] = 0.0f;

    for (int k0 = 0; k0 < 512; k0 += 64) {
        __syncthreads();
        *(uint4*)&As[sr * 72 + so]     = pA0;
        *(uint4*)&As[sr * 72 + so + 8] = pA1;
        *(uint4*)&Bs[sr * 72 + so]     = pB0;
        *(uint4*)&Bs[sr * 72 + so + 8] = pB1;
        __syncthreads();
        if (k0 + 64 < 512) {
            const f16_t* ap = A   + (size_t)(m0 + sr) * 512 + k0 + 64 + so;
            const f16_t* bp = Wot + (size_t)(n0 + sr) * 512 + k0 + 64 + so;
            pA0 = *(const uint4*)(ap); pA1 = *(const uint4*)(ap + 8);
            pB0 = *(const uint4*)(bp); pB1 = *(const uint4*)(bp + 8);
        }

        #pragma unroll
        for (int kc = 0; kc < 4; ++kc) {
            H8 a, b;
            a.u = *(const uint4*)&As[(mw + l31) * 72 + kc * 16 + half * 8];
            b.u = *(const uint4*)&Bs[(nw + l31) * 72 + kc * 16 + half * 8];
            acc = __builtin_amdgcn_mfma_f32_32x32x16_f16(a.v, b.v, acc, 0, 0, 0);
        }
    }

    const int n = n0 + nw + l31;
    const float bias0 = bias[n];
    #pragma unroll
    for (int r = 0; r < 16; ++r) {
        int m = m0 + mw + (r & 3) + 8 * (r >> 2) + 4 * half;
        C[(size_t)m * 512 + n] = acc[r] + bias0;
    }
}

// ---------------------------------------------------------------------------
extern "C" void kernel_launch(void* const* d_in, const int* in_sizes, int n_in,
                              void* d_out, int out_size, void* d_ws, size_t ws_size,
                              hipStream_t stream)
{
    const float* x_q = (const float*)d_in[0];
    const float* x_k = (const float*)d_in[1];
    const float* x_v = (const float*)d_in[2];
    const float* Wq  = (const float*)d_in[3];
    const float* bq  = (const float*)d_in[4];
    const float* Wk  = (const float*)d_in[5];
    const float* bk  = (const float*)d_in[6];
    const float* Wv  = (const float*)d_in[7];
    const float* bv  = (const float*)d_in[8];
    const float* Wo  = (const float*)d_in[9];
    const float* bo  = (const float*)d_in[10];
    float* out = (float*)d_out;

    // ws layout (~34 MB, unchanged)
    char* W = (char*)d_ws;
    bf16_t* Wtq = (bf16_t*)W;                                    // 512 KB
    bf16_t* Wtk = Wtq + (size_t)8 * 64 * 512;
    bf16_t* Wtv = Wtk + (size_t)8 * 64 * 512;
    f16_t*  Wot = (f16_t*)(Wtv + (size_t)8 * 64 * 512);          // 512 KB
    bf16_t* Qb  = (bf16_t*)(Wot + (size_t)512 * 512);            // 8 MB
    bf16_t* Kb  = Qb + (size_t)M_ * 512;                         // 8 MB
    bf16_t* Vt  = Kb + (size_t)M_ * 512;                         // 8 MB
    f16_t*  AO  = (f16_t*)(Vt + (size_t)M_ * 512);               // 8 MB

    // bf16 X scratch lives in DEAD buffers: d_out (16MB, rewritten by
    // gemm_out_tiled) holds Xq+Xk; the AO region (rewritten by attn) holds Xv.
    bf16_t* Xqb = (bf16_t*)out;                  // 8 MB
    bf16_t* Xkb = Xqb + (size_t)M_ * 512;        // 8 MB
    bf16_t* Xvb = (bf16_t*)AO;                   // 8 MB

    prep<<<dim3(3328), 256, 0, stream>>>(
        x_q, x_k, x_v, Xqb, Xkb, Xvb,
        Wq, Wk, Wv, Wo, Wtq, Wtk, Wtv, Wot);

    proj_tiled<<<dim3(64, 4, 3), 256, 0, stream>>>(
        Xqb, Xkb, Xvb, Wtq, Wtk, Wtv, bq, bk, bv, Qb, Kb, Vt);

    attn_mfma<<<dim3(S_ / 256, B_ * H_), 512, 0, stream>>>(Qb, Kb, Vt, AO);

    gemm_out_tiled<<<dim3(128, 8), 256, 0, stream>>>(AO, Wot, bo, out);
}